// Round 10
// baseline (291.754 us; speedup 1.0000x reference)
//
#include <hip/hip_runtime.h>

#define NN 100000
#define NE 1600000
#define NBUCK 196       // ceil(NN/512) buckets of 512 nodes
#define BUCKCAP 11520   // packed-pair slots per bucket (avg 8192, +36 sigma)
#define SCAP 13312      // ssrc slots per bucket (>= bucket_total + 7*512 at +17 sigma)
#define ACHUNK 8192     // edges per partition block

typedef _Float16 f16x8 __attribute__((ext_vector_type(8)));
typedef float f32x4 __attribute__((ext_vector_type(4)));

// ---------------- workspace layout (bytes) ----------------
static const size_t OFF_GCUR  = 0;                         // 256 ints
static const size_t OFF_META  = 1024;                      // NN int4 {beg, padded_deg, inv_deg bits, 0}
static const size_t OFF_SSRC  = 1601024;                   // NBUCK*SCAP ints = 10.4MB
static const size_t OFF_PAIRS = 12037632;                  // NBUCK*BUCKCAP ints = 9.0MB
static const size_t OFF_B1    = 21069312;                  // 128x256 f16
static const size_t OFF_B2    = 21134848;
static const size_t OFF_X16   = 21200384;                  // (N+1)*128 f16 (row N = zeros)
static const size_t OFF_H16   = 46800640;                  // (N+1)*128 f16 (row N = zeros)
// end 72.4MB

static __device__ inline float h2f(uint bits) {
    return (float)__builtin_bit_cast(_Float16, (ushort)bits);
}
static __device__ inline ushort f2h(float f) {
    return __builtin_bit_cast(ushort, (_Float16)f);
}
static __device__ inline uint pk2h(float a, float b) {
    return (uint)f2h(a) | ((uint)f2h(b) << 16);
}

__global__ void zero_dummy(ushort* __restrict__ a, ushort* __restrict__ b) {
    int t = threadIdx.x;
    a[(size_t)NN * 128 + t] = 0;
    b[(size_t)NN * 128 + t] = 0;
}

__global__ void init_gcur(int* __restrict__ gcur) {
    gcur[threadIdx.x] = threadIdx.x * BUCKCAP;
}

// single-pass radix partition: LDS-reorder each 8192-edge chunk bucket-contiguously,
// stream out dense runs of packed (src<<9 | dst&511) ints
__global__ __launch_bounds__(256) void partition_pairs(const int* __restrict__ src,
                                                       const int* __restrict__ dst,
                                                       int* __restrict__ gcur,
                                                       int* __restrict__ pairs, int ne) {
    __shared__ int2 staged[ACHUNK];   // 64KB {packed, dst}
    __shared__ int  dcache[ACHUNK];   // 32KB
    __shared__ int  hist[256], scanb[256], gbase[256];
    const int t = threadIdx.x;
    const int base = blockIdx.x * ACHUNK;
    const int n = min(ACHUNK, ne - base);

    hist[t] = 0;
    __syncthreads();
    for (int i = t; i < n; i += 256) {
        int d = dst[base + i];
        dcache[i] = d;
        atomicAdd(&hist[d >> 9], 1);
    }
    __syncthreads();

    int v = hist[t];
    scanb[t] = v;
    __syncthreads();
    for (int off = 1; off < 256; off <<= 1) {
        int x = (t >= off) ? scanb[t - off] : 0;
        __syncthreads();
        scanb[t] += x;
        __syncthreads();
    }
    int excl = scanb[t] - v;
    __syncthreads();
    scanb[t] = excl;
    hist[t] = 0;
    gbase[t] = (v > 0) ? atomicAdd(&gcur[t], v) : 0;
    __syncthreads();

    for (int i = t; i < n; i += 256) {
        int d = dcache[i];
        int b = d >> 9;
        int lp = scanb[b] + atomicAdd(&hist[b], 1);
        int2 pr;
        pr.x = (src[base + i] << 9) | (d & 511);
        pr.y = d;
        staged[lp] = pr;
    }
    __syncthreads();

    for (int i = t; i < n; i += 256) {
        int2 pr = staged[i];
        int b = pr.y >> 9;
        pairs[gbase[b] + (i - scanb[b])] = pr.x;
    }
}

// one block per bucket: LDS histogram -> scan -> meta -> pad-fill -> window-local scatter
__global__ __launch_bounds__(512) void bucket_build(const int* __restrict__ gcur,
                                                    const int* __restrict__ pairs,
                                                    int4* __restrict__ meta,
                                                    int* __restrict__ ssrc) {
    __shared__ int s[512];
    __shared__ int exclA[512];
    __shared__ int cur[512];
    const int b = blockIdx.x;
    const int t = threadIdx.x;
    const int pbeg = b * BUCKCAP;
    const int pend = gcur[b];
    const int sbase = b * SCAP;

    cur[t] = 0;
    __syncthreads();
    for (int i = pbeg + t; i < pend; i += 512)
        atomicAdd(&cur[pairs[i] & 511], 1);
    __syncthreads();

    const int deg = cur[t];
    const int pc = (deg + 7) & ~7;
    s[t] = pc;
    __syncthreads();
    for (int off = 1; off < 512; off <<= 1) {
        int x = (t >= off) ? s[t - off] : 0;
        __syncthreads();
        s[t] += x;
        __syncthreads();
    }
    const int excl = s[t] - pc;
    exclA[t] = excl;
    const int node = (b << 9) + t;
    if (node < NN) {
        int4 m;
        m.x = sbase + excl;
        m.y = pc;
        m.z = __builtin_bit_cast(int, 1.0f / (float)(deg > 1 ? deg : 1));
        m.w = 0;
        meta[node] = m;
    }
    __syncthreads();
    const int total = s[511];
    for (int i = t; i < total; i += 512)
        ssrc[sbase + i] = NN;
    cur[t] = 0;
    __syncthreads();
    for (int i = pbeg + t; i < pend; i += 512) {
        int p = pairs[i];
        int loc = p & 511;
        int pos = atomicAdd(&cur[loc], 1);
        ssrc[sbase + exclA[loc] + pos] = p >> 9;
    }
}

// fp32 [n][128] -> f16 [n][128]
__global__ void to_f16(const float* __restrict__ in, ushort* __restrict__ out, int n4) {
    int i = blockIdx.x * blockDim.x + threadIdx.x;
    if (i < n4) {
        float4 v = ((const float4*)in)[i];
        uint2 o;
        o.x = pk2h(v.x, v.y);
        o.y = pk2h(v.z, v.w);
        ((uint2*)out)[i] = o;
    }
}

// pack [Wl;Wr] into Bt f16 [n][k'=256]
__global__ void prep_w(const float* __restrict__ Wl, const float* __restrict__ Wr,
                       ushort* __restrict__ Bt) {
    int id = blockIdx.x * blockDim.x + threadIdx.x;
    if (id >= 32768) return;
    int nw = id & 127;
    int km = id >> 7;
    const float* W = (km < 128) ? Wl : Wr;
    int k = km & 127;
    Bt[(size_t)nw * 256 + km] = f2h(W[k * 128 + nw]);
}

// ---- fused layer body, 64-row tile (6+ blocks/CU for gather latency hiding):
//      phase 1: 4 waves x 16 nodes gather+mean into swizzled LDS (16KB);
//      phase 2: C(64x128) = [agg | feat] @ Bt, wave tile 32x64, acc[2][4];
//      B frags and feat-half of A read direct from L2/L3.
#define FUSED_BODY(FEAT)                                                               \
    const int t = threadIdx.x;                                                         \
    const int l = t & 63;                                                              \
    const int w = t >> 6;                                                              \
    const int rowBase = blockIdx.x * 64;                                               \
    /* ---- phase 1 ---- */                                                            \
    {                                                                                  \
        const int nodeBase = rowBase + w * 16;                                         \
        for (int i = 0; i < 16; ++i) {                                                 \
            const int node = nodeBase + i;                                             \
            const int r = w * 16 + i;                                                  \
            float s0 = 0.f, s1 = 0.f, s2 = 0.f, s3 = 0.f,                              \
                  s4 = 0.f, s5 = 0.f, s6 = 0.f, s7 = 0.f;                              \
            float id = 0.f;                                                            \
            if (node < n) {                                                            \
                const int4 m = meta[node];                                             \
                id = __builtin_bit_cast(float, m.z);                                   \
                int e = m.x;                                                           \
                const int end = m.x + m.y;                                             \
                const size_t loff = (size_t)(l * 2);                                   \
                if (e < end) {                                                         \
                    int4 c0 = *(const int4*)(ssrc + e);                                \
                    int4 c1 = *(const int4*)(ssrc + e + 4);                            \
                    for (; e < end; e += 8) {                                          \
                        int4 d0 = c0, d1 = c1;                                         \
                        int pn = (e + 8 < end) ? e + 8 : e;                            \
                        c0 = *(const int4*)(ssrc + pn);                                \
                        c1 = *(const int4*)(ssrc + pn + 4);                            \
                        uint v0 = *(const uint*)(FEAT + (size_t)d0.x * 128 + loff);    \
                        uint v1 = *(const uint*)(FEAT + (size_t)d0.y * 128 + loff);    \
                        uint v2 = *(const uint*)(FEAT + (size_t)d0.z * 128 + loff);    \
                        uint v3 = *(const uint*)(FEAT + (size_t)d0.w * 128 + loff);    \
                        uint v4 = *(const uint*)(FEAT + (size_t)d1.x * 128 + loff);    \
                        uint v5 = *(const uint*)(FEAT + (size_t)d1.y * 128 + loff);    \
                        uint v6 = *(const uint*)(FEAT + (size_t)d1.z * 128 + loff);    \
                        uint v7 = *(const uint*)(FEAT + (size_t)d1.w * 128 + loff);    \
                        s0 += h2f(v0 & 0xffffu); s1 += h2f(v0 >> 16);                  \
                        s2 += h2f(v1 & 0xffffu); s3 += h2f(v1 >> 16);                  \
                        s0 += h2f(v2 & 0xffffu); s1 += h2f(v2 >> 16);                  \
                        s2 += h2f(v3 & 0xffffu); s3 += h2f(v3 >> 16);                  \
                        s4 += h2f(v4 & 0xffffu); s5 += h2f(v4 >> 16);                  \
                        s6 += h2f(v5 & 0xffffu); s7 += h2f(v5 >> 16);                  \
                        s4 += h2f(v6 & 0xffffu); s5 += h2f(v6 >> 16);                  \
                        s6 += h2f(v7 & 0xffffu); s7 += h2f(v7 >> 16);                  \
                    }                                                                  \
                }                                                                      \
            }                                                                          \
            *(uint*)(smem + r * 256 + ((l * 4) ^ ((r & 7) << 4))) =                    \
                pk2h((s0 + s2 + s4 + s6) * id, (s1 + s3 + s5 + s7) * id);              \
        }                                                                              \
    }                                                                                  \
    __syncthreads();                                                                   \
    /* ---- phase 2 ---- */                                                            \
    const int wr = (w & 1) * 32, wc = (w >> 1) * 64;                                   \
    f32x4 acc[2][4];                                                                   \
    _Pragma("unroll")                                                                  \
    for (int i = 0; i < 2; ++i)                                                        \
        _Pragma("unroll")                                                              \
        for (int j = 0; j < 4; ++j) acc[i][j] = 0.0f;                                  \
    _Pragma("unroll")                                                                  \
    for (int kc = 0; kc < 8; ++kc) {                                                   \
        f16x8 af[2], bf[4];                                                            \
        _Pragma("unroll")                                                              \
        for (int i = 0; i < 2; ++i) {                                                  \
            const int r = wr + i * 16 + (l & 15);                                      \
            if (kc < 4) {                                                              \
                af[i] = *(const f16x8*)(smem + r * 256 +                               \
                         ((kc * 64 + (l >> 4) * 16) ^ ((r & 7) << 4)));                \
            } else {                                                                   \
                int grow = rowBase + r;                                                \
                if (grow >= n) grow = n - 1;                                           \
                af[i] = *(const f16x8*)(FEAT + (size_t)grow * 128 +                    \
                                        (kc - 4) * 32 + (l >> 4) * 8);                 \
            }                                                                          \
        }                                                                              \
        _Pragma("unroll")                                                              \
        for (int j = 0; j < 4; ++j) {                                                  \
            const int cn = wc + j * 16 + (l & 15);                                     \
            bf[j] = *(const f16x8*)(Bt + (size_t)cn * 256 + kc * 32 + (l >> 4) * 8);   \
        }                                                                              \
        _Pragma("unroll")                                                              \
        for (int i = 0; i < 2; ++i)                                                    \
            _Pragma("unroll")                                                          \
            for (int j = 0; j < 4; ++j)                                                \
                acc[i][j] = __builtin_amdgcn_mfma_f32_16x16x32_f16(af[i], bf[j],       \
                                                                   acc[i][j], 0, 0, 0); \
    }

// layer 1: h16 = relu(mean_agg(x16)@W1l + x16@W1r + b1), coalesced f16 store
__global__ __launch_bounds__(256, 6) void fused_layer1(const ushort* __restrict__ feat,
                                                       const int4* __restrict__ meta,
                                                       const int* __restrict__ ssrc,
                                                       const ushort* __restrict__ Bt,
                                                       const float* __restrict__ bias,
                                                       ushort* __restrict__ outH, int n) {
    __shared__ __align__(16) char smem[16384];
    FUSED_BODY(feat)

    __syncthreads();
    ushort* sOut = (ushort*)smem;   // 64 x 128 f16 = 16KB
#pragma unroll
    for (int j = 0; j < 4; ++j) {
        int col = wc + j * 16 + (l & 15);
        float bb = bias[col];
#pragma unroll
        for (int i = 0; i < 2; ++i)
#pragma unroll
            for (int q = 0; q < 4; ++q) {
                int row = wr + i * 16 + (l >> 4) * 4 + q;
                sOut[row * 128 + col] = f2h(fmaxf(acc[i][j][q] + bb, 0.f));
            }
    }
    __syncthreads();
    // full 16KB tile: 4 passes x 256 threads x 16B, coalesced
#pragma unroll
    for (int k = 0; k < 4; ++k) {
        int row = k * 16 + (t >> 4);
        int4 v = *(const int4*)(smem + k * 4096 + t * 16);
        if (rowBase + row < n)
            *(int4*)(outH + (size_t)(rowBase + row) * 128 + (t & 15) * 8) = v;
    }
}

// layer 2 + final linear: out = relu(mean_agg(h16)@W2l + h16@W2r + b2) @ Wlin + blin
__global__ __launch_bounds__(256, 6) void fused_layer2(const ushort* __restrict__ feat,
                                                       const int4* __restrict__ meta,
                                                       const int* __restrict__ ssrc,
                                                       const ushort* __restrict__ Bt,
                                                       const float* __restrict__ bias,
                                                       const float* __restrict__ Wlin,
                                                       const float* __restrict__ blin,
                                                       float* __restrict__ out, int n) {
    __shared__ __align__(16) char smem[16384];
    FUSED_BODY(feat)

    // per-thread partial dot with Wlin over its 4 columns
    float bb[4], wl0[4], wl1[4];
#pragma unroll
    for (int j = 0; j < 4; ++j) {
        int col = wc + j * 16 + (l & 15);
        bb[j]  = bias[col];
        float2 wv = *(const float2*)&Wlin[col * 2];
        wl0[j] = wv.x;
        wl1[j] = wv.y;
    }
    __syncthreads();
    float* sP = (float*)smem;   // [64 rows][32 slots][2] = 16KB
    const int p = (w >> 1) * 16 + (l & 15);
#pragma unroll
    for (int i = 0; i < 2; ++i)
#pragma unroll
        for (int q = 0; q < 4; ++q) {
            int row = wr + i * 16 + (l >> 4) * 4 + q;
            float p0 = 0.f, p1 = 0.f;
#pragma unroll
            for (int j = 0; j < 4; ++j) {
                float v = fmaxf(acc[i][j][q] + bb[j], 0.f);
                p0 += v * wl0[j];
                p1 += v * wl1[j];
            }
            int sidx = (p + row) & 31;   // row-keyed slot swizzle (store side)
            sP[row * 64 + sidx * 2 + 0] = p0;
            sP[row * 64 + sidx * 2 + 1] = p1;
        }
    __syncthreads();

    // 128 threads reduce 128 outputs (64 rows x 2 comps); read slots row-rotated
    if (t < 128) {
        const int row = t >> 1, comp = t & 1;
        float s = 0.f;
#pragma unroll
        for (int k = 0; k < 32; ++k)
            s += sP[row * 64 + (((k + row) & 31)) * 2 + comp];
        if (rowBase + row < n)
            out[(size_t)(rowBase + row) * 2 + comp] = s + blin[comp];
    }
}

extern "C" void kernel_launch(void* const* d_in, const int* in_sizes, int n_in,
                              void* d_out, int out_size, void* d_ws, size_t ws_size,
                              hipStream_t stream) {
    const float* x    = (const float*)d_in[0];
    const int*   ei   = (const int*)d_in[1];
    const float* W1l  = (const float*)d_in[2];
    const float* b1   = (const float*)d_in[3];
    const float* W1r  = (const float*)d_in[4];
    const float* W2l  = (const float*)d_in[5];
    const float* b2   = (const float*)d_in[6];
    const float* W2r  = (const float*)d_in[7];
    const float* Wlin = (const float*)d_in[8];
    const float* blin = (const float*)d_in[9];
    float* out = (float*)d_out;

    char* ws = (char*)d_ws;
    int*    gcur    = (int*)(ws + OFF_GCUR);
    int4*   meta    = (int4*)(ws + OFF_META);
    int*    ssrc    = (int*)(ws + OFF_SSRC);
    int*    pairs   = (int*)(ws + OFF_PAIRS);
    ushort* B1c     = (ushort*)(ws + OFF_B1);
    ushort* B2c     = (ushort*)(ws + OFF_B2);
    ushort* x16     = (ushort*)(ws + OFF_X16);
    ushort* h16     = (ushort*)(ws + OFF_H16);

    const int* src = ei;
    const int* dst = ei + NE;

    // weight packing + f16 conversion + dummy zero rows
    prep_w<<<128, 256, 0, stream>>>(W1l, W1r, B1c);
    prep_w<<<128, 256, 0, stream>>>(W2l, W2r, B2c);
    to_f16<<<(NN * 32 + 255) / 256, 256, 0, stream>>>(x, x16, NN * 32);
    zero_dummy<<<1, 128, 0, stream>>>(x16, h16);

    // CSR build: radix partition -> per-bucket LDS count/scan/fill
    init_gcur<<<1, 256, 0, stream>>>(gcur);
    partition_pairs<<<(NE + ACHUNK - 1) / ACHUNK, 256, 0, stream>>>(src, dst, gcur, pairs, NE);
    bucket_build<<<NBUCK, 512, 0, stream>>>(gcur, pairs, meta, ssrc);

    // layer 1 (fused aggregate + GEMM), 64-row tiles
    fused_layer1<<<(NN + 63) / 64, 256, 0, stream>>>(x16, meta, ssrc, B1c, b1, h16, NN);

    // layer 2 (fused aggregate + GEMM + final linear)
    fused_layer2<<<(NN + 63) / 64, 256, 0, stream>>>(h16, meta, ssrc, B2c, b2, Wlin, blin, out, NN);
}

// Round 11
// 260.388 us; speedup vs baseline: 1.1205x; 1.1205x over previous
//
#include <hip/hip_runtime.h>

#define NN 100000
#define NE 1600000
#define NBUCK 196       // ceil(NN/512) buckets of 512 nodes
#define BUCKCAP 11520   // packed-pair slots per bucket (avg 8192, +36 sigma)
#define SCAP 13312      // ssrc slots per bucket
#define ACHUNK 8192     // edges per partition block

typedef _Float16 f16x8 __attribute__((ext_vector_type(8)));
typedef float f32x4 __attribute__((ext_vector_type(4)));

// ---------------- workspace layout (bytes) ----------------
static const size_t OFF_GCUR  = 0;                         // 256 ints
static const size_t OFF_META  = 1024;                      // NN int4
static const size_t OFF_SSRC  = 1601024;                   // NBUCK*SCAP ints
static const size_t OFF_PAIRS = 12037632;                  // NBUCK*BUCKCAP ints
static const size_t OFF_B1    = 21069312;                  // 128x256 f16
static const size_t OFF_B2    = 21134848;
static const size_t OFF_X16   = 21200384;                  // (N+1)*128 f16 (row N = zeros)
static const size_t OFF_H16   = 46800640;                  // (N+1)*128 f16 (row N = zeros)
static const size_t OFF_AGG   = 72400896;                  // N*128 f16
// end 98.0MB

static __device__ inline float h2f(uint bits) {
    return (float)__builtin_bit_cast(_Float16, (ushort)bits);
}
static __device__ inline ushort f2h(float f) {
    return __builtin_bit_cast(ushort, (_Float16)f);
}
static __device__ inline uint pk2h(float a, float b) {
    return (uint)f2h(a) | ((uint)f2h(b) << 16);
}

__global__ void zero_dummy(ushort* __restrict__ a, ushort* __restrict__ b) {
    int t = threadIdx.x;
    a[(size_t)NN * 128 + t] = 0;
    b[(size_t)NN * 128 + t] = 0;
}

__global__ void init_gcur(int* __restrict__ gcur) {
    gcur[threadIdx.x] = threadIdx.x * BUCKCAP;
}

// single-pass radix partition (unchanged, validated r5-r10)
__global__ __launch_bounds__(256) void partition_pairs(const int* __restrict__ src,
                                                       const int* __restrict__ dst,
                                                       int* __restrict__ gcur,
                                                       int* __restrict__ pairs, int ne) {
    __shared__ int2 staged[ACHUNK];
    __shared__ int  dcache[ACHUNK];
    __shared__ int  hist[256], scanb[256], gbase[256];
    const int t = threadIdx.x;
    const int base = blockIdx.x * ACHUNK;
    const int n = min(ACHUNK, ne - base);

    hist[t] = 0;
    __syncthreads();
    for (int i = t; i < n; i += 256) {
        int d = dst[base + i];
        dcache[i] = d;
        atomicAdd(&hist[d >> 9], 1);
    }
    __syncthreads();

    int v = hist[t];
    scanb[t] = v;
    __syncthreads();
    for (int off = 1; off < 256; off <<= 1) {
        int x = (t >= off) ? scanb[t - off] : 0;
        __syncthreads();
        scanb[t] += x;
        __syncthreads();
    }
    int excl = scanb[t] - v;
    __syncthreads();
    scanb[t] = excl;
    hist[t] = 0;
    gbase[t] = (v > 0) ? atomicAdd(&gcur[t], v) : 0;
    __syncthreads();

    for (int i = t; i < n; i += 256) {
        int d = dcache[i];
        int b = d >> 9;
        int lp = scanb[b] + atomicAdd(&hist[b], 1);
        int2 pr;
        pr.x = (src[base + i] << 9) | (d & 511);
        pr.y = d;
        staged[lp] = pr;
    }
    __syncthreads();

    for (int i = t; i < n; i += 256) {
        int2 pr = staged[i];
        int b = pr.y >> 9;
        pairs[gbase[b] + (i - scanb[b])] = pr.x;
    }
}

// per-bucket CSR build (unchanged, validated)
__global__ __launch_bounds__(512) void bucket_build(const int* __restrict__ gcur,
                                                    const int* __restrict__ pairs,
                                                    int4* __restrict__ meta,
                                                    int* __restrict__ ssrc) {
    __shared__ int s[512];
    __shared__ int exclA[512];
    __shared__ int cur[512];
    const int b = blockIdx.x;
    const int t = threadIdx.x;
    const int pbeg = b * BUCKCAP;
    const int pend = gcur[b];
    const int sbase = b * SCAP;

    cur[t] = 0;
    __syncthreads();
    for (int i = pbeg + t; i < pend; i += 512)
        atomicAdd(&cur[pairs[i] & 511], 1);
    __syncthreads();

    const int deg = cur[t];
    const int pc = (deg + 7) & ~7;
    s[t] = pc;
    __syncthreads();
    for (int off = 1; off < 512; off <<= 1) {
        int x = (t >= off) ? s[t - off] : 0;
        __syncthreads();
        s[t] += x;
        __syncthreads();
    }
    const int excl = s[t] - pc;
    exclA[t] = excl;
    const int node = (b << 9) + t;
    if (node < NN) {
        int4 m;
        m.x = sbase + excl;
        m.y = pc;
        m.z = __builtin_bit_cast(int, 1.0f / (float)(deg > 1 ? deg : 1));
        m.w = 0;
        meta[node] = m;
    }
    __syncthreads();
    const int total = s[511];
    for (int i = t; i < total; i += 512)
        ssrc[sbase + i] = NN;
    cur[t] = 0;
    __syncthreads();
    for (int i = pbeg + t; i < pend; i += 512) {
        int p = pairs[i];
        int loc = p & 511;
        int pos = atomicAdd(&cur[loc], 1);
        ssrc[sbase + exclA[loc] + pos] = p >> 9;
    }
}

// fp32 [n][128] -> f16 [n][128]
__global__ void to_f16(const float* __restrict__ in, ushort* __restrict__ out, int n4) {
    int i = blockIdx.x * blockDim.x + threadIdx.x;
    if (i < n4) {
        float4 v = ((const float4*)in)[i];
        uint2 o;
        o.x = pk2h(v.x, v.y);
        o.y = pk2h(v.z, v.w);
        ((uint2*)out)[i] = o;
    }
}

// pack [Wl;Wr] into Bt f16 [n][k'=256]
__global__ void prep_w(const float* __restrict__ Wl, const float* __restrict__ Wr,
                       ushort* __restrict__ Bt) {
    int id = blockIdx.x * blockDim.x + threadIdx.x;
    if (id >= 32768) return;
    int nw = id & 127;
    int km = id >> 7;
    const float* W = (km < 128) ? Wl : Wr;
    int k = km & 127;
    Bt[(size_t)nw * 256 + km] = f2h(W[k * 128 + nw]);
}

// issue 8 independent feature-row gathers into named regs
#define ISSUE(p, C0, C1)                                                  \
    p##0 = *(const uint*)(feat + (size_t)(C0).x * 128 + loff);            \
    p##1 = *(const uint*)(feat + (size_t)(C0).y * 128 + loff);            \
    p##2 = *(const uint*)(feat + (size_t)(C0).z * 128 + loff);            \
    p##3 = *(const uint*)(feat + (size_t)(C0).w * 128 + loff);            \
    p##4 = *(const uint*)(feat + (size_t)(C1).x * 128 + loff);            \
    p##5 = *(const uint*)(feat + (size_t)(C1).y * 128 + loff);            \
    p##6 = *(const uint*)(feat + (size_t)(C1).z * 128 + loff);            \
    p##7 = *(const uint*)(feat + (size_t)(C1).w * 128 + loff);

#define CONSUME(p)                                                        \
    s0 += h2f(p##0 & 0xffffu); s1 += h2f(p##0 >> 16);                     \
    s2 += h2f(p##1 & 0xffffu); s3 += h2f(p##1 >> 16);                     \
    s0 += h2f(p##2 & 0xffffu); s1 += h2f(p##2 >> 16);                     \
    s2 += h2f(p##3 & 0xffffu); s3 += h2f(p##3 >> 16);                     \
    s4 += h2f(p##4 & 0xffffu); s5 += h2f(p##4 >> 16);                     \
    s6 += h2f(p##5 & 0xffffu); s7 += h2f(p##5 >> 16);                     \
    s4 += h2f(p##6 & 0xffffu); s5 += h2f(p##6 >> 16);                     \
    s6 += h2f(p##7 & 0xffffu); s7 += h2f(p##7 >> 16);

// one wave per node; 2-group software pipeline -> 16 gathers in flight
__global__ __launch_bounds__(256, 6) void aggregate16(const ushort* __restrict__ feat,
                                                      const int4* __restrict__ meta,
                                                      const int* __restrict__ ssrc,
                                                      ushort* __restrict__ outv, int n) {
    int wave = (blockIdx.x * blockDim.x + threadIdx.x) >> 6;
    int lane = threadIdx.x & 63;
    if (wave >= n) return;
    const int4 m = meta[wave];
    int e = m.x;
    const int end = m.x + m.y;
    const float id = __builtin_bit_cast(float, m.z);
    const size_t loff = (size_t)(lane * 2);
    float s0 = 0.f, s1 = 0.f, s2 = 0.f, s3 = 0.f, s4 = 0.f, s5 = 0.f, s6 = 0.f, s7 = 0.f;
    uint a0, a1, a2, a3, a4, a5, a6, a7;
    uint b0, b1, b2, b3, b4, b5, b6, b7;

    if (e < end) {
        int4 c0 = *(const int4*)(ssrc + e);
        int4 c1 = *(const int4*)(ssrc + e + 4);
        ISSUE(a, c0, c1)
        e += 8;
        if (e < end) {
            c0 = *(const int4*)(ssrc + e);
            c1 = *(const int4*)(ssrc + e + 4);
            ISSUE(b, c0, c1)
            e += 8;
            while (e < end) {
                c0 = *(const int4*)(ssrc + e);
                c1 = *(const int4*)(ssrc + e + 4);
                CONSUME(a)
                ISSUE(a, c0, c1)
                e += 8;
                if (e >= end) break;
                c0 = *(const int4*)(ssrc + e);
                c1 = *(const int4*)(ssrc + e + 4);
                CONSUME(b)
                ISSUE(b, c0, c1)
                e += 8;
            }
            CONSUME(a)
            CONSUME(b)
        } else {
            CONSUME(a)
        }
    }
    *(uint*)&outv[(size_t)wave * 128 + loff] =
        pk2h((s0 + s2 + s4 + s6) * id, (s1 + s3 + s5 + s7) * id);
}

// ---- barrier-free GEMM main loop: 64-row tile, wave tile 32x64, all operands
//      read direct from L2/L3 (Bt 64KB L2-hot; A rows L2/L3-resident) ----
#define GEMM_DIRECT(AOP, XOP)                                                          \
    const int t = threadIdx.x;                                                         \
    const int l = t & 63;                                                              \
    const int w = t >> 6;                                                              \
    const int rowBase = blockIdx.x * 64;                                               \
    const int wr = (w & 1) * 32, wc = (w >> 1) * 64;                                   \
    f32x4 acc[2][4];                                                                   \
    _Pragma("unroll")                                                                  \
    for (int i = 0; i < 2; ++i)                                                        \
        _Pragma("unroll")                                                              \
        for (int j = 0; j < 4; ++j) acc[i][j] = 0.0f;                                  \
    int grow_[2];                                                                      \
    _Pragma("unroll")                                                                  \
    for (int i = 0; i < 2; ++i) {                                                      \
        int r = rowBase + wr + i * 16 + (l & 15);                                      \
        grow_[i] = (r < n) ? r : (n - 1);                                              \
    }                                                                                  \
    _Pragma("unroll")                                                                  \
    for (int kc = 0; kc < 8; ++kc) {                                                   \
        f16x8 af[2], bf[4];                                                            \
        const ushort* srcA = (kc < 4) ? (AOP) : (XOP);                                 \
        _Pragma("unroll")                                                              \
        for (int i = 0; i < 2; ++i)                                                    \
            af[i] = *(const f16x8*)(srcA + (size_t)grow_[i] * 128 +                    \
                                    (kc & 3) * 32 + (l >> 4) * 8);                     \
        _Pragma("unroll")                                                              \
        for (int j = 0; j < 4; ++j) {                                                  \
            const int cn = wc + j * 16 + (l & 15);                                     \
            bf[j] = *(const f16x8*)(Bt + (size_t)cn * 256 + kc * 32 + (l >> 4) * 8);   \
        }                                                                              \
        _Pragma("unroll")                                                              \
        for (int i = 0; i < 2; ++i)                                                    \
            _Pragma("unroll")                                                          \
            for (int j = 0; j < 4; ++j)                                                \
                acc[i][j] = __builtin_amdgcn_mfma_f32_16x16x32_f16(af[i], bf[j],       \
                                                                   acc[i][j], 0, 0, 0); \
    }

// layer 1: h16 = relu(agg@W1l + x@W1r + b1), LDS-staged coalesced f16 store
__global__ __launch_bounds__(256, 6) void gemm1(const ushort* __restrict__ Aop,
                                                const ushort* __restrict__ Xop,
                                                const ushort* __restrict__ Bt,
                                                const float* __restrict__ bias,
                                                ushort* __restrict__ outH, int n) {
    __shared__ __align__(16) char smem[16384];
    GEMM_DIRECT(Aop, Xop)

    ushort* sOut = (ushort*)smem;   // 64 x 128 f16 = 16KB
#pragma unroll
    for (int j = 0; j < 4; ++j) {
        int col = wc + j * 16 + (l & 15);
        float bb = bias[col];
#pragma unroll
        for (int i = 0; i < 2; ++i)
#pragma unroll
            for (int q = 0; q < 4; ++q) {
                int row = wr + i * 16 + (l >> 4) * 4 + q;
                sOut[row * 128 + col] = f2h(fmaxf(acc[i][j][q] + bb, 0.f));
            }
    }
    __syncthreads();
#pragma unroll
    for (int k = 0; k < 4; ++k) {
        int row = k * 16 + (t >> 4);
        int4 v = *(const int4*)(smem + k * 4096 + t * 16);
        if (rowBase + row < n)
            *(int4*)(outH + (size_t)(rowBase + row) * 128 + (t & 15) * 8) = v;
    }
}

// layer 2 + fused final linear: out = relu(agg@W2l + h@W2r + b2) @ Wlin + blin
__global__ __launch_bounds__(256, 6) void gemm2(const ushort* __restrict__ Aop,
                                                const ushort* __restrict__ Xop,
                                                const ushort* __restrict__ Bt,
                                                const float* __restrict__ bias,
                                                const float* __restrict__ Wlin,
                                                const float* __restrict__ blin,
                                                float* __restrict__ out, int n) {
    __shared__ __align__(16) char smem[16384];
    GEMM_DIRECT(Aop, Xop)

    float bb[4], wl0[4], wl1[4];
#pragma unroll
    for (int j = 0; j < 4; ++j) {
        int col = wc + j * 16 + (l & 15);
        bb[j]  = bias[col];
        float2 wv = *(const float2*)&Wlin[col * 2];
        wl0[j] = wv.x;
        wl1[j] = wv.y;
    }
    float* sP = (float*)smem;   // [64 rows][32 slots][2] = 16KB
    const int p = (w >> 1) * 16 + (l & 15);
#pragma unroll
    for (int i = 0; i < 2; ++i)
#pragma unroll
        for (int q = 0; q < 4; ++q) {
            int row = wr + i * 16 + (l >> 4) * 4 + q;
            float p0 = 0.f, p1 = 0.f;
#pragma unroll
            for (int j = 0; j < 4; ++j) {
                float v = fmaxf(acc[i][j][q] + bb[j], 0.f);
                p0 += v * wl0[j];
                p1 += v * wl1[j];
            }
            int sidx = (p + row) & 31;   // row-keyed slot swizzle
            sP[row * 64 + sidx * 2 + 0] = p0;
            sP[row * 64 + sidx * 2 + 1] = p1;
        }
    __syncthreads();

    if (t < 128) {
        const int row = t >> 1, comp = t & 1;
        float s = 0.f;
#pragma unroll
        for (int k = 0; k < 32; ++k)
            s += sP[row * 64 + (((k + row) & 31)) * 2 + comp];
        if (rowBase + row < n)
            out[(size_t)(rowBase + row) * 2 + comp] = s + blin[comp];
    }
}

extern "C" void kernel_launch(void* const* d_in, const int* in_sizes, int n_in,
                              void* d_out, int out_size, void* d_ws, size_t ws_size,
                              hipStream_t stream) {
    const float* x    = (const float*)d_in[0];
    const int*   ei   = (const int*)d_in[1];
    const float* W1l  = (const float*)d_in[2];
    const float* b1   = (const float*)d_in[3];
    const float* W1r  = (const float*)d_in[4];
    const float* W2l  = (const float*)d_in[5];
    const float* b2   = (const float*)d_in[6];
    const float* W2r  = (const float*)d_in[7];
    const float* Wlin = (const float*)d_in[8];
    const float* blin = (const float*)d_in[9];
    float* out = (float*)d_out;

    char* ws = (char*)d_ws;
    int*    gcur    = (int*)(ws + OFF_GCUR);
    int4*   meta    = (int4*)(ws + OFF_META);
    int*    ssrc    = (int*)(ws + OFF_SSRC);
    int*    pairs   = (int*)(ws + OFF_PAIRS);
    ushort* B1c     = (ushort*)(ws + OFF_B1);
    ushort* B2c     = (ushort*)(ws + OFF_B2);
    ushort* x16     = (ushort*)(ws + OFF_X16);
    ushort* h16     = (ushort*)(ws + OFF_H16);
    ushort* agg16   = (ushort*)(ws + OFF_AGG);

    const int* src = ei;
    const int* dst = ei + NE;

    // weight packing + f16 conversion + dummy zero rows
    prep_w<<<128, 256, 0, stream>>>(W1l, W1r, B1c);
    prep_w<<<128, 256, 0, stream>>>(W2l, W2r, B2c);
    to_f16<<<(NN * 32 + 255) / 256, 256, 0, stream>>>(x, x16, NN * 32);
    zero_dummy<<<1, 128, 0, stream>>>(x16, h16);

    // CSR build
    init_gcur<<<1, 256, 0, stream>>>(gcur);
    partition_pairs<<<(NE + ACHUNK - 1) / ACHUNK, 256, 0, stream>>>(src, dst, gcur, pairs, NE);
    bucket_build<<<NBUCK, 512, 0, stream>>>(gcur, pairs, meta, ssrc);

    // layer 1
    aggregate16<<<(NN * 64 + 255) / 256, 256, 0, stream>>>(x16, meta, ssrc, agg16, NN);
    gemm1<<<(NN + 63) / 64, 256, 0, stream>>>(agg16, x16, B1c, b1, h16, NN);

    // layer 2 + fused final linear
    aggregate16<<<(NN * 64 + 255) / 256, 256, 0, stream>>>(h16, meta, ssrc, agg16, NN);
    gemm2<<<(NN + 63) / 64, 256, 0, stream>>>(agg16, h16, B2c, b2, Wlin, blin, out, NN);
}